// Round 2
// baseline (222.478 us; speedup 1.0000x reference)
//
#include <hip/hip_runtime.h>
#include <stdint.h>

typedef __attribute__((ext_vector_type(4))) float f32x4;
typedef __attribute__((ext_vector_type(8))) short bf16x8;
typedef __attribute__((ext_vector_type(4))) unsigned short u16x4;

#define AS1(p) ((const __attribute__((address_space(1))) void*)(p))
#define AS3(p) ((__attribute__((address_space(3))) void*)(p))

__device__ __forceinline__ unsigned short f2bf(float f){
  unsigned u = __builtin_bit_cast(unsigned, f);
  u += 0x7FFF + ((u >> 16) & 1);     // round-to-nearest-even
  return (unsigned short)(u >> 16);
}

// ---------- cast f32 -> bf16, 4 elems/thread ----------
__global__ __launch_bounds__(256) void k_cast(const float* __restrict__ in,
                                              unsigned short* __restrict__ out, int n4){
  int i = blockIdx.x*256 + threadIdx.x;
  if (i >= n4) return;
  f32x4 v = ((const f32x4*)in)[i];
  u16x4 o;
  o.x = f2bf(v.x); o.y = f2bf(v.y); o.z = f2bf(v.z); o.w = f2bf(v.w);
  ((u16x4*)out)[i] = o;
}

// ---------- transpose + cast: in f32 [R][C] -> out bf16 [C][R] ----------
__global__ __launch_bounds__(256) void k_transpose_cast(const float* __restrict__ in,
                                                        unsigned short* __restrict__ out,
                                                        int R, int C){
  __shared__ float tile[32][33];
  int tx = threadIdx.x & 31, ty = threadIdx.x >> 5;       // 32 x 8
  int c0 = blockIdx.x*32, r0 = blockIdx.y*32;
  #pragma unroll
  for (int i = 0; i < 4; i++)
    tile[ty + i*8][tx] = in[(size_t)(r0 + ty + i*8)*C + c0 + tx];
  __syncthreads();
  #pragma unroll
  for (int i = 0; i < 4; i++)
    out[(size_t)(c0 + ty + i*8)*R + r0 + tx] = f2bf(tile[tx][ty + i*8]);
}

// ---------- bf16 GEMM:  out[M][N] = act(A[M][K] @ Bt[N][K]^T + bias) ----------
// 128x128 tile, 4 waves (2x2), each wave 64x64 via 4x4 of 16x16x32 MFMA.
template<bool RELU, bool OUTBF16>
__global__ __launch_bounds__(256) void k_gemm(const unsigned short* __restrict__ A,
                                              const unsigned short* __restrict__ Bt,
                                              const float* __restrict__ bias,
                                              void* __restrict__ out, int K, int N){
  __shared__ short As[128*32];
  __shared__ short Bs[128*32];
  const int tid  = threadIdx.x;
  const int lane = tid & 63, wid = tid >> 6;
  const int wr = wid >> 1, wc = wid & 1;
  const int l15 = lane & 15, lk = lane >> 4;
  const int bm = blockIdx.x, bn = blockIdx.y;

  // staging: thread -> (row = tid/4 [+64], k-elem = (tid%4)*8), 16B each
  const unsigned short* Ab = A  + (size_t)bm*128*K + (size_t)(tid >> 2)*K + (tid & 3)*8;
  const unsigned short* Bb = Bt + (size_t)bn*128*K + (size_t)(tid >> 2)*K + (tid & 3)*8;
  short* AsD = &As[tid*8];
  short* BsD = &Bs[tid*8];

  f32x4 acc[4][4];
  #pragma unroll
  for (int i = 0; i < 4; i++)
    #pragma unroll
    for (int j = 0; j < 4; j++) acc[i][j] = (f32x4){0.f,0.f,0.f,0.f};

  for (int k0 = 0; k0 < K; k0 += 32){
    __builtin_amdgcn_global_load_lds(AS1(Ab + k0),        AS3(AsD),        16, 0, 0);
    __builtin_amdgcn_global_load_lds(AS1(Ab + 64*K + k0), AS3(AsD + 2048), 16, 0, 0);
    __builtin_amdgcn_global_load_lds(AS1(Bb + k0),        AS3(BsD),        16, 0, 0);
    __builtin_amdgcn_global_load_lds(AS1(Bb + 64*K + k0), AS3(BsD + 2048), 16, 0, 0);
    __syncthreads();

    bf16x8 af[4], bg[4];
    #pragma unroll
    for (int i = 0; i < 4; i++)
      af[i] = *(const bf16x8*)&As[(wr*64 + i*16 + l15)*32 + lk*8];
    #pragma unroll
    for (int j = 0; j < 4; j++)
      bg[j] = *(const bf16x8*)&Bs[(wc*64 + j*16 + l15)*32 + lk*8];
    #pragma unroll
    for (int i = 0; i < 4; i++)
      #pragma unroll
      for (int j = 0; j < 4; j++)
        acc[i][j] = __builtin_amdgcn_mfma_f32_16x16x32_bf16(af[i], bg[j], acc[i][j], 0, 0, 0);
    __syncthreads();
  }

  // epilogue: C/D layout col = lane&15, row = (lane>>4)*4 + r
  const int row0 = bm*128 + wr*64 + lk*4;
  const int col0 = bn*128 + wc*64 + l15;
  #pragma unroll
  for (int i = 0; i < 4; i++){
    #pragma unroll
    for (int j = 0; j < 4; j++){
      int col = col0 + j*16;
      float b = bias[col];
      #pragma unroll
      for (int r = 0; r < 4; r++){
        int row = row0 + i*16 + r;
        float v = acc[i][j][r] + b;
        if (RELU) v = fmaxf(v, 0.f);
        if (OUTBF16) ((unsigned short*)out)[(size_t)row*N + col] = f2bf(v);
        else         ((float*)out)[(size_t)row*N + col] = v;
      }
    }
  }
}

// ---------- KNN phase 1: per (h, l-part) partial top-3 ----------
#define NL 8192
#define LP 8
#define CH 1024

__global__ __launch_bounds__(256) void k_knn_partial(const float* __restrict__ l_pos,
                                                     const float* __restrict__ h_pos,
                                                     float* __restrict__ pd,
                                                     int* __restrict__ pi){
  __shared__ float sx[CH], sy[CH], sz[CH];
  const int part = blockIdx.y;
  const int tid  = threadIdx.x;
  const int h    = blockIdx.x*256 + tid;
  for (int t = tid; t < CH; t += 256){
    int g = part*CH + t;
    sx[t] = l_pos[g*3+0];
    sy[t] = l_pos[g*3+1];
    sz[t] = l_pos[g*3+2];
  }
  __syncthreads();
  const float hx = h_pos[h*3+0], hy = h_pos[h*3+1], hz = h_pos[h*3+2];
  float d0 = 3e38f, d1 = 3e38f, d2 = 3e38f;
  int   i0 = -1,    i1 = -1,    i2 = -1;
  #pragma unroll 4
  for (int j = 0; j < CH; j++){
    float dx = hx - sx[j], dy = hy - sy[j], dz = hz - sz[j];
    float d = fmaf(dx, dx, fmaf(dy, dy, dz*dz));
    if (d < d2){
      int jg = part*CH + j;
      if (d < d1){
        d2 = d1; i2 = i1;
        if (d < d0){ d1 = d0; i1 = i0; d0 = d; i0 = jg; }
        else       { d1 = d;  i1 = jg; }
      } else { d2 = d; i2 = jg; }
    }
  }
  int base = (h*LP + part)*3;
  pd[base+0] = d0; pd[base+1] = d1; pd[base+2] = d2;
  pi[base+0] = i0; pi[base+1] = i1; pi[base+2] = i2;
}

// ---------- KNN phase 2: merge 8 partials -> weights + indices ----------
__global__ __launch_bounds__(256) void k_knn_merge(const float* __restrict__ pd,
                                                   const int* __restrict__ pi,
                                                   float* __restrict__ w,
                                                   int* __restrict__ idx){
  const int h = blockIdx.x*256 + threadIdx.x;
  float d0 = 3e38f, d1 = 3e38f, d2 = 3e38f;
  int   i0 = 0,     i1 = 0,     i2 = 0;
  #pragma unroll
  for (int p = 0; p < LP; p++){
    #pragma unroll
    for (int k = 0; k < 3; k++){
      float d = pd[(h*LP + p)*3 + k];
      int  ii = pi[(h*LP + p)*3 + k];
      if (d < d2){
        if (d < d1){
          d2 = d1; i2 = i1;
          if (d < d0){ d1 = d0; i1 = i0; d0 = d; i0 = ii; }
          else       { d1 = d;  i1 = ii; }
        } else { d2 = d; i2 = ii; }
      }
    }
  }
  w[h*3+0] = 1.0f/fmaxf(d0, 1e-16f); idx[h*3+0] = i0;
  w[h*3+1] = 1.0f/fmaxf(d1, 1e-16f); idx[h*3+1] = i1;
  w[h*3+2] = 1.0f/fmaxf(d2, 1e-16f); idx[h*3+2] = i2;
}

// ---------- KNN phase 3: gather l_y rows, weighted avg, add into out ----------
__global__ __launch_bounds__(256) void k_knn_gather(const float* __restrict__ w,
                                                    const int* __restrict__ idx,
                                                    const float* __restrict__ l_y,
                                                    float* __restrict__ out){
  const int t = blockIdx.x*256 + threadIdx.x;
  const int h = t >> 5, lane = t & 31;               // 32 lanes x float4 = 128 feats
  const float w0 = w[h*3+0], w1 = w[h*3+1], w2 = w[h*3+2];
  const int   j0 = idx[h*3+0], j1 = idx[h*3+1], j2 = idx[h*3+2];
  const f32x4* ly4 = (const f32x4*)l_y;
  f32x4 a = ly4[(size_t)j0*32 + lane]*w0
          + ly4[(size_t)j1*32 + lane]*w1
          + ly4[(size_t)j2*32 + lane]*w2;
  float inv = 1.0f/(w0 + w1 + w2);
  f32x4* o4 = (f32x4*)out;
  size_t oi = (size_t)h*32 + lane;
  o4[oi] = o4[oi] + a*inv;
}

extern "C" void kernel_launch(void* const* d_in, const int* in_sizes, int n_in,
                              void* d_out, int out_size, void* d_ws, size_t ws_size,
                              hipStream_t stream){
  const float* emb   = (const float*)d_in[0];
  const float* l_y   = (const float*)d_in[1];
  const float* l_pos = (const float*)d_in[2];
  const float* h_pos = (const float*)d_in[3];
  const float* W1    = (const float*)d_in[4];
  const float* b1    = (const float*)d_in[5];
  const float* W2    = (const float*)d_in[6];
  const float* b2    = (const float*)d_in[7];
  const float* W3    = (const float*)d_in[8];
  const float* b3    = (const float*)d_in[9];

  const int M = 32768, H = 512, O = 128;

  char* ws = (char*)d_ws;
  unsigned short* bufA = (unsigned short*)(ws);                  // 32 MB: emb_bf16, later X2
  unsigned short* bufB = (unsigned short*)(ws + 33554432);       // 32 MB: X1
  unsigned short* W1t  = (unsigned short*)(ws + 67108864);       // 512 KB
  unsigned short* W2t  = (unsigned short*)(ws + 67633152);       // 512 KB
  unsigned short* W3t  = (unsigned short*)(ws + 68157440);       // 128 KB
  float* pd  = (float*)(ws + 68288512);                          // 3 MB
  int*   pi  = (int*)  (ws + 71434240);                          // 3 MB
  float* wts = (float*)(ws + 74579968);                          // 384 KB
  int*   idx = (int*)  (ws + 74973184);                          // 384 KB

  // casts / transposes
  k_cast<<<dim3(M*H/4/256), 256, 0, stream>>>(emb, bufA, M*H/4);
  k_transpose_cast<<<dim3(H/32, H/32), 256, 0, stream>>>(W1, W1t, H, H);
  k_transpose_cast<<<dim3(H/32, H/32), 256, 0, stream>>>(W2, W2t, H, H);
  k_transpose_cast<<<dim3(O/32, H/32), 256, 0, stream>>>(W3, W3t, H, O);

  // MLP
  k_gemm<true,  true ><<<dim3(M/128, H/128), 256, 0, stream>>>(bufA, W1t, b1, bufB, H, H);
  k_gemm<true,  true ><<<dim3(M/128, H/128), 256, 0, stream>>>(bufB, W2t, b2, bufA, H, H);
  k_gemm<false, false><<<dim3(M/128, O/128), 256, 0, stream>>>(bufA, W3t, b3, d_out, H, O);

  // KNN interpolate (+= into out)
  k_knn_partial<<<dim3(M/256, LP), 256, 0, stream>>>(l_pos, h_pos, pd, pi);
  k_knn_merge<<<dim3(M/256), 256, 0, stream>>>(pd, pi, wts, idx);
  k_knn_gather<<<dim3(M*32/256), 256, 0, stream>>>(wts, idx, l_y, (float*)d_out);
}